// Round 17
// baseline (1501.141 us; speedup 1.0000x reference)
//
#include <hip/hip_runtime.h>
#include <hip/hip_bf16.h>
#include <cstddef>
#include <cstdint>

// Model dims (fixed by the reference)
#define VOCAB 50257
#define VPAD  50432              // 197 * 256 (lm-head B rows padded for 256-tile)
#define DMODEL 1024
#define NHEAD 8
#define NLAYER 6
#define SEQ 1024
#define BATCH 2
#define HDIM 128
#define FFDIM 4096
#define NTOK (SEQ * BATCH)       // 2048 tokens
#define QKVLD 3072               // fused q|k|v row stride
#define EPSV 1e-5f

// Token layout is BATCH-MAJOR throughout: token' = b*SEQ + s.

typedef __attribute__((ext_vector_type(8))) short short8;
typedef __attribute__((ext_vector_type(4))) float f32x4;

__device__ __forceinline__ unsigned short f2bf(float f) {
    union { float f; unsigned u; } v; v.f = f;
    unsigned r = v.u + 0x7FFF + ((v.u >> 16) & 1);   // round-to-nearest-even
    return (unsigned short)(r >> 16);
}

// ---------------------------------------------------------------------------
// Embedding (batch-major)
// ---------------------------------------------------------------------------
__global__ __launch_bounds__(256) void embed_kernel(
    const int* __restrict__ tokens, const float* __restrict__ tok_emb,
    const float* __restrict__ pos_emb, float* __restrict__ x)
{
    int idx = blockIdx.x * 256 + threadIdx.x;
    int t = idx >> 10;                    // b*SEQ + s
    int d = idx & (DMODEL - 1);
    int b = t >> 10, s = t & (SEQ - 1);
    int tok = tokens[s * BATCH + b];
    x[idx] = tok_emb[(size_t)tok * DMODEL + d] + pos_emb[(size_t)s * DMODEL + d];
}

// ---------------------------------------------------------------------------
// RMSNorm f32 -> bf16. WAVE-PER-TOKEN: 64 lanes handle one 1024-elem row
// (4 float4/lane), shfl_xor reduction — zero barriers. 4 tokens/block.
// ---------------------------------------------------------------------------
__global__ __launch_bounds__(256) void rmsnorm_bf_kernel(
    const float* __restrict__ x, const float* __restrict__ w,
    unsigned short* __restrict__ o)
{
    const int wave = threadIdx.x >> 6, lane = threadIdx.x & 63;
    const int t = blockIdx.x * 4 + wave;
    const float4* xr = (const float4*)(x + (size_t)t * DMODEL);
    const float4* wr = (const float4*)w;
    float4 xv[4];
    float ss = 0.f;
    #pragma unroll
    for (int j = 0; j < 4; ++j) {
        xv[j] = xr[lane + 64 * j];
        ss += xv[j].x * xv[j].x + xv[j].y * xv[j].y
            + xv[j].z * xv[j].z + xv[j].w * xv[j].w;
    }
    #pragma unroll
    for (int off = 1; off < 64; off <<= 1) ss += __shfl_xor(ss, off);
    float inv = rsqrtf(ss * (1.0f / DMODEL) + EPSV);
    ushort4* orow = (ushort4*)(o + (size_t)t * DMODEL);
    #pragma unroll
    for (int j = 0; j < 4; ++j) {
        float4 wv = wr[lane + 64 * j];
        ushort4 ov;
        ov.x = f2bf(wv.x * xv[j].x * inv);
        ov.y = f2bf(wv.y * xv[j].y * inv);
        ov.z = f2bf(wv.z * xv[j].z * inv);
        ov.w = f2bf(wv.w * xv[j].w * inv);
        orow[lane + 64 * j] = ov;
    }
}

// ---------------------------------------------------------------------------
// Batched transpose + cast: in [z][R][C] f32 -> out [z][C][R] bf16
// ---------------------------------------------------------------------------
__global__ __launch_bounds__(256) void transpose_cast_kernel(
    const float* __restrict__ in, unsigned short* __restrict__ out, int R, int C)
{
    __shared__ float tile[32][33];
    const size_t bo = (size_t)blockIdx.z * R * C;
    const float* src = in + bo;
    unsigned short* dst = out + bo;
    int c0 = blockIdx.x * 32, r0 = blockIdx.y * 32;
    int tx = threadIdx.x, ty = threadIdx.y;
    #pragma unroll
    for (int i = 0; i < 32; i += 8)
        tile[ty + i][tx] = src[(size_t)(r0 + ty + i) * C + c0 + tx];
    __syncthreads();
    #pragma unroll
    for (int i = 0; i < 32; i += 8)
        dst[(size_t)(c0 + ty + i) * R + r0 + tx] = f2bf(tile[tx][ty + i]);
}

// ---------------------------------------------------------------------------
// Q/K/V weight transpose into combined Wqkv_t [l][3072][1024] at row offset.
// ---------------------------------------------------------------------------
__global__ __launch_bounds__(256) void transpose_qkv_kernel(
    const float* __restrict__ in, unsigned short* __restrict__ out, int row_off)
{
    __shared__ float tile[32][33];
    int z = blockIdx.z;
    int l = z >> 3, h = z & 7;
    const float* src = in + (size_t)z * DMODEL * HDIM;
    unsigned short* dst = out + (size_t)l * QKVLD * DMODEL
                              + (size_t)(row_off + h * HDIM) * DMODEL;
    int c0 = blockIdx.x * 32, r0 = blockIdx.y * 32;
    int tx = threadIdx.x, ty = threadIdx.y;
    #pragma unroll
    for (int i = 0; i < 32; i += 8)
        tile[ty + i][tx] = src[(size_t)(r0 + ty + i) * HDIM + c0 + tx];
    __syncthreads();
    #pragma unroll
    for (int i = 0; i < 32; i += 8)
        dst[(size_t)(c0 + ty + i) * DMODEL + r0 + tx] = f2bf(tile[tx][ty + i]);
}

// ---------------------------------------------------------------------------
// Vt transpose: qkv [token][3072] (cols 2048..3071) -> vt [hd][token] bf16
// ---------------------------------------------------------------------------
__global__ __launch_bounds__(256) void vt_transpose_kernel(
    const unsigned short* __restrict__ qkv, unsigned short* __restrict__ vt)
{
    __shared__ unsigned short tile[32][33];
    int c0 = blockIdx.x * 32;   // hd
    int r0 = blockIdx.y * 32;   // token
    int tx = threadIdx.x, ty = threadIdx.y;
    #pragma unroll
    for (int i = 0; i < 32; i += 8)
        tile[ty + i][tx] = qkv[(size_t)(r0 + ty + i) * QKVLD + 2048 + c0 + tx];
    __syncthreads();
    #pragma unroll
    for (int i = 0; i < 32; i += 8)
        vt[(size_t)(c0 + ty + i) * NTOK + r0 + tx] = tile[tx][ty + i];
}

// ---------------------------------------------------------------------------
// f32 -> bf16 flat cast with zero padding
// ---------------------------------------------------------------------------
__global__ __launch_bounds__(256) void cast_pad_kernel(
    const float* __restrict__ in, unsigned short* __restrict__ out,
    long n_src, long n_tot)
{
    long i = ((long)blockIdx.x * 256 + threadIdx.x) * 8;
    if (i >= n_tot) return;
    short8 o8;
    if (i < n_src) {
        const float4* p = (const float4*)(in + i);
        float4 a = p[0], b = p[1];
        o8[0] = (short)f2bf(a.x); o8[1] = (short)f2bf(a.y);
        o8[2] = (short)f2bf(a.z); o8[3] = (short)f2bf(a.w);
        o8[4] = (short)f2bf(b.x); o8[5] = (short)f2bf(b.y);
        o8[6] = (short)f2bf(b.z); o8[7] = (short)f2bf(b.w);
    } else {
        o8 = (short8)0;
    }
    *(short8*)(out + i) = o8;
}

// ---------------------------------------------------------------------------
// mm128: 128x128-tile bf16 MFMA GEMM, BK=32, 4-deep LDS ring (64KB ->
// 2 blocks/CU) + counted vmcnt. Swizzle (row>>1)&3: 0 conflicts (r11/r12 PMC).
// ---------------------------------------------------------------------------
template<bool ATOMIC, bool SILU, bool BF16OUT, int RM>
__global__ __launch_bounds__(256, 2) void mm128_kernel(
    const unsigned short* __restrict__ A, const unsigned short* __restrict__ Bt,
    void* __restrict__ Cv, int M, int N, int K, int rows, int ksplit)
{
    int nwg = gridDim.x;
    int flat = blockIdx.x;
    int q8 = nwg >> 3, r8 = nwg & 7;
    int xcd = flat & 7, lid = flat >> 3;
    int wg = (r8 == 0) ? (xcd * q8 + lid)
           : ((xcd < r8 ? xcd * (q8 + 1) : r8 * (q8 + 1) + (xcd - r8) * q8) + lid);
    int rs = rows * ksplit;
    const int col0 = (wg / rs) * 128;
    int rem = wg % rs;
    const int row0 = (rem / ksplit) * 128;
    const int sk   = rem % ksplit;
    const int Keff = K / ksplit;
    const int kbase = sk * Keff;

    __shared__ __align__(16) char lds[65536];   // 4 bufs x (A 8KB + B 8KB)
    const int tid  = threadIdx.x;
    const int lane = tid & 63;
    const int wave = tid >> 6;
    const int wm = wave >> 1, wn = wave & 1;
    const int g  = lane >> 4;
    const int c  = lane & 15;

    f32x4 acc[4][4] = {};

    auto STAGE = [&](int buf, int t) {
        const int k0 = kbase + t * 32;
        char* base = lds + buf * 16384;
        #pragma unroll
        for (int j = 0; j < 2; ++j) {
            int chunk = j * 256 + tid;
            int row = chunk >> 2, slot = chunk & 3;
            int ss = slot ^ ((row >> 1) & 3);
            __builtin_amdgcn_global_load_lds(
                (const __attribute__((address_space(1))) void*)
                    (A + (size_t)(row0 + row) * K + k0 + ss * 8),
                (__attribute__((address_space(3))) void*)(base + chunk * 16), 16, 0, 0);
        }
        #pragma unroll
        for (int j = 0; j < 2; ++j) {
            int chunk = j * 256 + tid;
            int row = chunk >> 2, slot = chunk & 3;
            int ss = slot ^ ((row >> 1) & 3);
            __builtin_amdgcn_global_load_lds(
                (const __attribute__((address_space(1))) void*)
                    (Bt + (size_t)(col0 + row) * K + k0 + ss * 8),
                (__attribute__((address_space(3))) void*)(base + 8192 + chunk * 16), 16, 0, 0);
        }
    };

    const int NT = Keff >> 5;
    STAGE(0, 0);
    if (NT > 1) STAGE(1, 1);
    if (NT > 2) STAGE(2, 2);
    if (NT > 2)      asm volatile("s_waitcnt vmcnt(8)" ::: "memory");
    else if (NT > 1) asm volatile("s_waitcnt vmcnt(4)" ::: "memory");
    else             asm volatile("s_waitcnt vmcnt(0)" ::: "memory");
    __builtin_amdgcn_s_barrier();
    __builtin_amdgcn_sched_barrier(0);

    for (int t = 0; t < NT; ++t) {
        if (t + 3 < NT) STAGE((t + 3) & 3, t + 3);

        char* base = lds + (t & 3) * 16384;
        short8 af[4], bf[4];
        #pragma unroll
        for (int i = 0; i < 4; ++i) {
            int rowa = wm * 64 + i * 16 + c;
            af[i] = *(const short8*)(base + rowa * 64 + ((g ^ ((rowa >> 1) & 3)) << 4));
            int rowb = wn * 64 + i * 16 + c;
            bf[i] = *(const short8*)(base + 8192 + rowb * 64 + ((g ^ ((rowb >> 1) & 3)) << 4));
        }
        __builtin_amdgcn_s_setprio(1);
        #pragma unroll
        for (int i = 0; i < 4; ++i)
            #pragma unroll
            for (int j = 0; j < 4; ++j)
                acc[i][j] = __builtin_amdgcn_mfma_f32_16x16x32_bf16(
                    af[i], bf[j], acc[i][j], 0, 0, 0);
        __builtin_amdgcn_s_setprio(0);
        __builtin_amdgcn_sched_barrier(0);

        if (t + 1 < NT) {
            if (t + 3 < NT)      asm volatile("s_waitcnt vmcnt(8)" ::: "memory");
            else if (t + 2 < NT) asm volatile("s_waitcnt vmcnt(4)" ::: "memory");
            else                 asm volatile("s_waitcnt vmcnt(0)" ::: "memory");
            __builtin_amdgcn_s_barrier();
            __builtin_amdgcn_sched_barrier(0);
        }
    }

    float* Cf = (float*)Cv;
    unsigned short* Cb = (unsigned short*)Cv;
    const int crow  = row0 + wm * 64 + g * 4;
    const int ccol0 = col0 + wn * 64 + c;
    #pragma unroll
    for (int i = 0; i < 4; ++i) {
        #pragma unroll
        for (int j = 0; j < 4; ++j) {
            int gcol = ccol0 + j * 16;
            if (gcol < N) {
                #pragma unroll
                for (int r = 0; r < 4; ++r) {
                    int grow = crow + i * 16 + r;
                    int orow = RM ? (((grow & (SEQ - 1)) << 1) | (grow >> 10)) : grow;
                    float v = acc[i][j][r];
                    if (SILU) v = v / (1.0f + __expf(-v));
                    size_t ci = (size_t)orow * N + gcol;
                    if (ATOMIC)       atomicAdd(&Cf[ci], v);
                    else if (BF16OUT) Cb[ci] = f2bf(v);
                    else              Cf[ci] = v;
                }
            }
        }
    }
}

// ---------------------------------------------------------------------------
// mm256: 256x256-tile, 8 waves, BK=32, 4-deep LDS ring (128KB, 1 block/CU),
// counted vmcnt, swizzle (row>>1)&3 — proven 306 us / 0 conflicts (r12).
// ---------------------------------------------------------------------------
template<bool SILU, bool BF16OUT, int RM>
__global__ __launch_bounds__(512, 1) void mm256_kernel(
    const unsigned short* __restrict__ A, const unsigned short* __restrict__ Bt,
    void* __restrict__ Cv, int M, int N, int K, int rows)
{
    int nwg = gridDim.x;
    int flat = blockIdx.x;
    int q8 = nwg >> 3, r8 = nwg & 7;
    int xcd = flat & 7, lid = flat >> 3;
    int wg = (r8 == 0) ? (xcd * q8 + lid)
           : ((xcd < r8 ? xcd * (q8 + 1) : r8 * (q8 + 1) + (xcd - r8) * q8) + lid);
    const int row0 = (wg % rows) * 256;
    const int col0 = (wg / rows) * 256;

    __shared__ __align__(16) char lds[131072];   // 4 bufs x (A 16KB + B 16KB)
    const int tid  = threadIdx.x;
    const int lane = tid & 63;
    const int wave = tid >> 6;
    const int wm = wave >> 2;
    const int wn = wave & 3;
    const int g  = lane >> 4;
    const int c  = lane & 15;

    f32x4 acc[8][4] = {};

    auto STAGE = [&](int buf, int tile) {
        const int k0 = tile * 32;
        char* base = lds + buf * 32768;
        #pragma unroll
        for (int j = 0; j < 2; ++j) {
            int chunk = j * 512 + tid;
            int row = chunk >> 2, slot = chunk & 3;
            int sslot = slot ^ ((row >> 1) & 3);
            __builtin_amdgcn_global_load_lds(
                (const __attribute__((address_space(1))) void*)
                    (A + (size_t)(row0 + row) * K + k0 + sslot * 8),
                (__attribute__((address_space(3))) void*)(base + chunk * 16), 16, 0, 0);
        }
        #pragma unroll
        for (int j = 0; j < 2; ++j) {
            int chunk = j * 512 + tid;
            int row = chunk >> 2, slot = chunk & 3;
            int sslot = slot ^ ((row >> 1) & 3);
            __builtin_amdgcn_global_load_lds(
                (const __attribute__((address_space(1))) void*)
                    (Bt + (size_t)(col0 + row) * K + k0 + sslot * 8),
                (__attribute__((address_space(3))) void*)(base + 16384 + chunk * 16), 16, 0, 0);
        }
    };

    const int NT = K >> 5;
    STAGE(0, 0); STAGE(1, 1); STAGE(2, 2);
    asm volatile("s_waitcnt vmcnt(8)" ::: "memory");
    __builtin_amdgcn_s_barrier();
    __builtin_amdgcn_sched_barrier(0);

    for (int t = 0; t < NT; ++t) {
        if (t + 3 < NT) STAGE((t + 3) & 3, t + 3);

        char* base = lds + (t & 3) * 32768;
        short8 af[8], bf[4];
        #pragma unroll
        for (int mf = 0; mf < 8; ++mf) {
            int row = wm * 128 + mf * 16 + c;
            af[mf] = *(const short8*)(base + row * 64 + ((g ^ ((row >> 1) & 3)) << 4));
        }
        #pragma unroll
        for (int nf = 0; nf < 4; ++nf) {
            int row = wn * 64 + nf * 16 + c;
            bf[nf] = *(const short8*)(base + 16384 + row * 64 + ((g ^ ((row >> 1) & 3)) << 4));
        }
        __builtin_amdgcn_s_setprio(1);
        #pragma unroll
        for (int mf = 0; mf < 8; ++mf)
            #pragma unroll
            for (int nf = 0; nf < 4; ++nf)
                acc[mf][nf] = __builtin_amdgcn_mfma_f32_16x16x32_bf16(
                    af[mf], bf[nf], acc[mf][nf], 0, 0, 0);
        __builtin_amdgcn_s_setprio(0);
        __builtin_amdgcn_sched_barrier(0);

        if (t + 1 < NT) {
            if (t + 3 < NT)      asm volatile("s_waitcnt vmcnt(8)" ::: "memory");
            else if (t + 2 < NT) asm volatile("s_waitcnt vmcnt(4)" ::: "memory");
            else                 asm volatile("s_waitcnt vmcnt(0)" ::: "memory");
            __builtin_amdgcn_s_barrier();
            __builtin_amdgcn_sched_barrier(0);
        }
    }

    float* Cf = (float*)Cv;
    unsigned short* Cb = (unsigned short*)Cv;
    #pragma unroll
    for (int mf = 0; mf < 8; ++mf) {
        #pragma unroll
        for (int nf = 0; nf < 4; ++nf) {
            int gcol = col0 + wn * 64 + nf * 16 + c;
            if (gcol < N) {
                #pragma unroll
                for (int r = 0; r < 4; ++r) {
                    int grow = row0 + wm * 128 + mf * 16 + g * 4 + r;
                    int orow = RM ? (((grow & (SEQ - 1)) << 1) | (grow >> 10)) : grow;
                    float v = acc[mf][nf][r];
                    if (SILU) v = v / (1.0f + __expf(-v));
                    size_t ci = (size_t)orow * N + gcol;
                    if (BF16OUT) Cb[ci] = f2bf(v);
                    else         Cf[ci] = v;
                }
            }
        }
    }
}

// ---------------------------------------------------------------------------
// Flash attention (bf16 MFMA). q,k from fused qkv (stride QKVLD); vt [hd][tok].
// ---------------------------------------------------------------------------
__global__ __launch_bounds__(256) void flash_attn_kernel(
    const unsigned short* __restrict__ q, const unsigned short* __restrict__ k,
    const unsigned short* __restrict__ vt, unsigned short* __restrict__ o)
{
    const int qt   = blockIdx.x;
    const int h    = blockIdx.y;
    const int b    = blockIdx.z;
    const int tid  = threadIdx.x;
    const int lane = tid & 63;
    const int wave = tid >> 6;
    const int g    = lane >> 4;
    const int c    = lane & 15;

    __shared__ unsigned short k_lds[64 * 128];
    __shared__ unsigned short vt_lds[128 * 64];
    __shared__ unsigned short p_lds[4 * 16 * 64];

    const int q0  = qt * 64;
    const int wq0 = q0 + wave * 16;
    const int tokb = b * SEQ;

    short8 qf[4];
    {
        const unsigned short* qr =
            q + (size_t)(tokb + wq0 + c) * QKVLD + h * HDIM + g * 8;
        #pragma unroll
        for (int dblk = 0; dblk < 4; ++dblk)
            qf[dblk] = *(const short8*)(qr + dblk * 32);
    }

    f32x4 oacc[8] = {};
    float m = -1e30f, l = 0.f;
    const float scale = 0.08838834764831845f;
    const int myq = wq0 + c;

    const int nt = qt + 1;
    for (int it = 0; it < nt; ++it) {
        const int kv0 = it * 64;
        short8 kc[4], vc[4];
        #pragma unroll
        for (int i = 0; i < 4; ++i) {
            int chunk = tid + i * 256;
            int key = chunk >> 4, cc = chunk & 15;
            kc[i] = *(const short8*)(
                k + (size_t)(tokb + kv0 + key) * QKVLD + h * HDIM + cc * 8);
        }
        #pragma unroll
        for (int i = 0; i < 4; ++i) {
            int chunk = tid + i * 256;
            int d = chunk >> 3, cc = chunk & 7;
            vc[i] = *(const short8*)(
                vt + (size_t)(h * HDIM + d) * NTOK + tokb + kv0 + cc * 8);
        }
        __syncthreads();
        #pragma unroll
        for (int i = 0; i < 4; ++i) {
            int chunk = tid + i * 256;
            int key = chunk >> 4, cc = chunk & 15;
            *(short8*)((char*)k_lds + ((key * 256 + cc * 16) ^ ((key & 7) << 4))) = kc[i];
        }
        #pragma unroll
        for (int i = 0; i < 4; ++i) {
            int chunk = tid + i * 256;
            int d = chunk >> 3, cc = chunk & 7;
            *(short8*)((char*)vt_lds + ((d * 128 + cc * 16) ^ ((d & 7) << 4))) = vc[i];
        }
        __syncthreads();

        f32x4 st[4];
        #pragma unroll
        for (int sub = 0; sub < 4; ++sub) {
            f32x4 acc = {};
            int key = sub * 16 + c;
            #pragma unroll
            for (int dblk = 0; dblk < 4; ++dblk) {
                short8 kf = *(const short8*)((char*)k_lds +
                    ((key * 256 + dblk * 64 + g * 16) ^ ((key & 7) << 4)));
                acc = __builtin_amdgcn_mfma_f32_16x16x32_bf16(kf, qf[dblk], acc, 0, 0, 0);
            }
            st[sub] = acc;
        }

        #pragma unroll
        for (int sub = 0; sub < 4; ++sub)
            #pragma unroll
            for (int r = 0; r < 4; ++r) {
                int key = kv0 + sub * 16 + g * 4 + r;
                float s = st[sub][r] * scale;
                st[sub][r] = (key <= myq) ? s : -1e30f;
            }

        float tm = -1e30f;
        #pragma unroll
        for (int sub = 0; sub < 4; ++sub)
            #pragma unroll
            for (int r = 0; r < 4; ++r) tm = fmaxf(tm, st[sub][r]);
        tm = fmaxf(tm, __shfl_xor(tm, 16));
        tm = fmaxf(tm, __shfl_xor(tm, 32));
        float mnew = fmaxf(m, tm);
        float sc_f = __expf(m - mnew);
        m = mnew;

        float ps = 0.f;
        #pragma unroll
        for (int sub = 0; sub < 4; ++sub) {
            float p0 = __expf(st[sub][0] - m);
            float p1 = __expf(st[sub][1] - m);
            float p2 = __expf(st[sub][2] - m);
            float p3 = __expf(st[sub][3] - m);
            ps += (p0 + p1) + (p2 + p3);
            ushort4 pk;
            pk.x = f2bf(p0); pk.y = f2bf(p1); pk.z = f2bf(p2); pk.w = f2bf(p3);
            *(ushort4*)((char*)p_lds + wave * 2048 +
                ((c * 128 + sub * 32 + g * 8) ^ ((c & 7) << 4))) = pk;
        }
        ps += __shfl_xor(ps, 16);
        ps += __shfl_xor(ps, 32);
        l = l * sc_f + ps;
        #pragma unroll
        for (int dt = 0; dt < 8; ++dt)
            #pragma unroll
            for (int r = 0; r < 4; ++r) oacc[dt][r] *= sc_f;

        #pragma unroll
        for (int kb = 0; kb < 2; ++kb) {
            short8 pf = *(const short8*)((char*)p_lds + wave * 2048 +
                ((c * 128 + kb * 64 + g * 16) ^ ((c & 7) << 4)));
            #pragma unroll
            for (int dt = 0; dt < 8; ++dt) {
                int d = dt * 16 + c;
                short8 vf = *(const short8*)((char*)vt_lds +
                    ((d * 128 + kb * 64 + g * 16) ^ ((d & 7) << 4)));
                oacc[dt] = __builtin_amdgcn_mfma_f32_16x16x32_bf16(vf, pf, oacc[dt], 0, 0, 0);
            }
        }
    }

    float inv = 1.0f / l;
    unsigned short* orow = o + (size_t)(tokb + wq0 + c) * DMODEL + h * HDIM + g * 4;
    #pragma unroll
    for (int dt = 0; dt < 8; ++dt) {
        ushort4 ov;
        ov.x = f2bf(oacc[dt][0] * inv);
        ov.y = f2bf(oacc[dt][1] * inv);
        ov.z = f2bf(oacc[dt][2] * inv);
        ov.w = f2bf(oacc[dt][3] * inv);
        *(ushort4*)(orow + dt * 16) = ov;
    }
}

// ---------------------------------------------------------------------------
// Launch
// ---------------------------------------------------------------------------
extern "C" void kernel_launch(void* const* d_in, const int* in_sizes, int n_in,
                              void* d_out, int out_size, void* d_ws, size_t ws_size,
                              hipStream_t stream)
{
    const int*   tokens       = (const int*)  d_in[0];
    const float* tok_emb      = (const float*)d_in[1];
    const float* pos_emb      = (const float*)d_in[2];
    const float* attn_norm_w  = (const float*)d_in[3];
    const float* Wq           = (const float*)d_in[4];
    const float* Wk           = (const float*)d_in[5];
    const float* Wv           = (const float*)d_in[6];
    const float* Wo           = (const float*)d_in[7];
    const float* mlp_norm_w   = (const float*)d_in[8];
    const float* W1           = (const float*)d_in[9];
    const float* W2           = (const float*)d_in[10];
    const float* final_norm_w = (const float*)d_in[11];
    float* out = (float*)d_out;

    // ---- workspace layout ----
    char* wp = (char*)d_ws;
    size_t off = 0;
    auto alloc = [&](size_t bytes) -> void* {
        void* p = wp + off;
        off += (bytes + 255) & ~(size_t)255;
        return p;
    };
    float* x             = (float*)alloc((size_t)NTOK * DMODEL * 4);
    unsigned short* nbf     = (unsigned short*)alloc((size_t)NTOK * DMODEL * 2);
    unsigned short* qkvbf   = (unsigned short*)alloc((size_t)NTOK * QKVLD * 2);
    unsigned short* vtb     = (unsigned short*)alloc((size_t)DMODEL * NTOK * 2);
    unsigned short* attnbf  = (unsigned short*)alloc((size_t)NTOK * DMODEL * 2);
    unsigned short* hbf     = (unsigned short*)alloc((size_t)NTOK * FFDIM * 2);
    unsigned short* temb    = (unsigned short*)alloc((size_t)VPAD * DMODEL * 2);
    unsigned short* Wqkv_t  = (unsigned short*)alloc((size_t)NLAYER * QKVLD * DMODEL * 2);
    unsigned short* Wo_t    = (unsigned short*)alloc((size_t)NLAYER * DMODEL * DMODEL * 2);
    unsigned short* W1_t    = (unsigned short*)alloc((size_t)NLAYER * DMODEL * FFDIM * 2);
    unsigned short* W2_t    = (unsigned short*)alloc((size_t)NLAYER * FFDIM * DMODEL * 2);
    if (off > ws_size) return;

    // ---- weight prep ----
    {
        dim3 bb(32, 8), g(HDIM / 32, DMODEL / 32, NLAYER * NHEAD);
        transpose_qkv_kernel<<<g, bb, 0, stream>>>(Wq, Wqkv_t, 0);
        transpose_qkv_kernel<<<g, bb, 0, stream>>>(Wk, Wqkv_t, DMODEL);
        transpose_qkv_kernel<<<g, bb, 0, stream>>>(Wv, Wqkv_t, 2 * DMODEL);
    }
    {
        dim3 bb(32, 8), g(DMODEL / 32, DMODEL / 32, NLAYER);
        transpose_cast_kernel<<<g, bb, 0, stream>>>(Wo, Wo_t, DMODEL, DMODEL);
    }
    {
        dim3 bb(32, 8), g(FFDIM / 32, DMODEL / 32, NLAYER);
        transpose_cast_kernel<<<g, bb, 0, stream>>>(W1, W1_t, DMODEL, FFDIM);
    }
    {
        dim3 bb(32, 8), g(DMODEL / 32, FFDIM / 32, NLAYER);
        transpose_cast_kernel<<<g, bb, 0, stream>>>(W2, W2_t, FFDIM, DMODEL);
    }
    {
        long n_src = (long)VOCAB * DMODEL, n_tot = (long)VPAD * DMODEL;
        cast_pad_kernel<<<(unsigned)(n_tot / 8 / 256), 256, 0, stream>>>(
            tok_emb, temb, n_src, n_tot);
    }

    // ---- embed ----
    embed_kernel<<<(NTOK * DMODEL) / 256, 256, 0, stream>>>(tokens, tok_emb, pos_emb, x);

    const size_t LW    = (size_t)DMODEL * DMODEL;
    const size_t LWQKV = (size_t)QKVLD * DMODEL;
    const size_t LWF   = (size_t)DMODEL * FFDIM;

    for (int l = 0; l < NLAYER; l++) {
        rmsnorm_bf_kernel<<<NTOK / 4, 256, 0, stream>>>(
            x, attn_norm_w + (size_t)l * DMODEL, nbf);
        // fused qkv: [NTOK][3072], 24 cols x 16 rows = 384 blocks
        mm128_kernel<false, false, true, 0><<<384, 256, 0, stream>>>(
            nbf, Wqkv_t + l * LWQKV, qkvbf, NTOK, QKVLD, DMODEL, 16, 1);
        vt_transpose_kernel<<<dim3(DMODEL / 32, NTOK / 32), dim3(32, 8), 0, stream>>>(
            qkvbf, vtb);
        flash_attn_kernel<<<dim3(SEQ / 64, NHEAD, BATCH), 256, 0, stream>>>(
            qkvbf, qkvbf + DMODEL, vtb, attnbf);
        // out proj: split-K=4 (512 blocks -> 2 blocks/CU TLP), atomic f32
        mm128_kernel<true, false, false, 0><<<8 * 16 * 4, 256, 0, stream>>>(
            attnbf, Wo_t + l * LW, x, NTOK, DMODEL, DMODEL, 16, 4);
        rmsnorm_bf_kernel<<<NTOK / 4, 256, 0, stream>>>(
            x, mlp_norm_w + (size_t)l * DMODEL, nbf);
        // h = silu(n @ W1): 32 cols x 16 rows = 512 blocks
        mm128_kernel<false, true, true, 0><<<32 * 16, 256, 0, stream>>>(
            nbf, W1_t + l * LWF, hbf, NTOK, FFDIM, DMODEL, 16, 1);
        // x += h @ W2: split-K=4 (512 blocks -> 2 blocks/CU TLP)
        mm128_kernel<true, false, false, 0><<<8 * 16 * 4, 256, 0, stream>>>(
            hbf, W2_t + l * LWF, x, NTOK, DMODEL, FFDIM, 16, 4);
    }

    rmsnorm_bf_kernel<<<NTOK / 4, 256, 0, stream>>>(x, final_norm_w, nbf);
    // lm-head: mm256 4-ring (proven 306 us), 8 rows x 197 cols = 1576 blocks
    mm256_kernel<false, false, 1><<<8 * 197, 512, 0, stream>>>(
        nbf, temb, out, NTOK, VOCAB, DMODEL, 8);
}

// Round 18
// 1410.488 us; speedup vs baseline: 1.0643x; 1.0643x over previous
//
#include <hip/hip_runtime.h>
#include <hip/hip_bf16.h>
#include <cstddef>
#include <cstdint>

// Model dims (fixed by the reference)
#define VOCAB 50257
#define VPAD  50432              // 197 * 256 (lm-head B rows padded for 256-tile)
#define DMODEL 1024
#define NHEAD 8
#define NLAYER 6
#define SEQ 1024
#define BATCH 2
#define HDIM 128
#define FFDIM 4096
#define NTOK (SEQ * BATCH)       // 2048 tokens
#define QKVLD 3072               // fused q|k|v row stride
#define EPSV 1e-5f

// Token layout is BATCH-MAJOR throughout: token' = b*SEQ + s.

typedef __attribute__((ext_vector_type(8))) short short8;
typedef __attribute__((ext_vector_type(4))) float f32x4;

__device__ __forceinline__ unsigned short f2bf(float f) {
    union { float f; unsigned u; } v; v.f = f;
    unsigned r = v.u + 0x7FFF + ((v.u >> 16) & 1);   // round-to-nearest-even
    return (unsigned short)(r >> 16);
}

// ---------------------------------------------------------------------------
// Embedding (batch-major)
// ---------------------------------------------------------------------------
__global__ __launch_bounds__(256) void embed_kernel(
    const int* __restrict__ tokens, const float* __restrict__ tok_emb,
    const float* __restrict__ pos_emb, float* __restrict__ x)
{
    int idx = blockIdx.x * 256 + threadIdx.x;
    int t = idx >> 10;                    // b*SEQ + s
    int d = idx & (DMODEL - 1);
    int b = t >> 10, s = t & (SEQ - 1);
    int tok = tokens[s * BATCH + b];
    x[idx] = tok_emb[(size_t)tok * DMODEL + d] + pos_emb[(size_t)s * DMODEL + d];
}

// ---------------------------------------------------------------------------
// RMSNorm f32 -> bf16. WAVE-PER-TOKEN: 64 lanes handle one 1024-elem row
// (4 float4/lane), shfl_xor reduction — zero barriers. 4 tokens/block.
// ---------------------------------------------------------------------------
__global__ __launch_bounds__(256) void rmsnorm_bf_kernel(
    const float* __restrict__ x, const float* __restrict__ w,
    unsigned short* __restrict__ o)
{
    const int wave = threadIdx.x >> 6, lane = threadIdx.x & 63;
    const int t = blockIdx.x * 4 + wave;
    const float4* xr = (const float4*)(x + (size_t)t * DMODEL);
    const float4* wr = (const float4*)w;
    float4 xv[4];
    float ss = 0.f;
    #pragma unroll
    for (int j = 0; j < 4; ++j) {
        xv[j] = xr[lane + 64 * j];
        ss += xv[j].x * xv[j].x + xv[j].y * xv[j].y
            + xv[j].z * xv[j].z + xv[j].w * xv[j].w;
    }
    #pragma unroll
    for (int off = 1; off < 64; off <<= 1) ss += __shfl_xor(ss, off);
    float inv = rsqrtf(ss * (1.0f / DMODEL) + EPSV);
    ushort4* orow = (ushort4*)(o + (size_t)t * DMODEL);
    #pragma unroll
    for (int j = 0; j < 4; ++j) {
        float4 wv = wr[lane + 64 * j];
        ushort4 ov;
        ov.x = f2bf(wv.x * xv[j].x * inv);
        ov.y = f2bf(wv.y * xv[j].y * inv);
        ov.z = f2bf(wv.z * xv[j].z * inv);
        ov.w = f2bf(wv.w * xv[j].w * inv);
        orow[lane + 64 * j] = ov;
    }
}

// ---------------------------------------------------------------------------
// Batched transpose + cast: in [z][R][C] f32 -> out [z][C][R] bf16
// ---------------------------------------------------------------------------
__global__ __launch_bounds__(256) void transpose_cast_kernel(
    const float* __restrict__ in, unsigned short* __restrict__ out, int R, int C)
{
    __shared__ float tile[32][33];
    const size_t bo = (size_t)blockIdx.z * R * C;
    const float* src = in + bo;
    unsigned short* dst = out + bo;
    int c0 = blockIdx.x * 32, r0 = blockIdx.y * 32;
    int tx = threadIdx.x, ty = threadIdx.y;
    #pragma unroll
    for (int i = 0; i < 32; i += 8)
        tile[ty + i][tx] = src[(size_t)(r0 + ty + i) * C + c0 + tx];
    __syncthreads();
    #pragma unroll
    for (int i = 0; i < 32; i += 8)
        dst[(size_t)(c0 + ty + i) * R + r0 + tx] = f2bf(tile[tx][ty + i]);
}

// ---------------------------------------------------------------------------
// Q/K/V weight transpose into combined Wqkv_t [l][3072][1024] at row offset.
// ---------------------------------------------------------------------------
__global__ __launch_bounds__(256) void transpose_qkv_kernel(
    const float* __restrict__ in, unsigned short* __restrict__ out, int row_off)
{
    __shared__ float tile[32][33];
    int z = blockIdx.z;
    int l = z >> 3, h = z & 7;
    const float* src = in + (size_t)z * DMODEL * HDIM;
    unsigned short* dst = out + (size_t)l * QKVLD * DMODEL
                              + (size_t)(row_off + h * HDIM) * DMODEL;
    int c0 = blockIdx.x * 32, r0 = blockIdx.y * 32;
    int tx = threadIdx.x, ty = threadIdx.y;
    #pragma unroll
    for (int i = 0; i < 32; i += 8)
        tile[ty + i][tx] = src[(size_t)(r0 + ty + i) * HDIM + c0 + tx];
    __syncthreads();
    #pragma unroll
    for (int i = 0; i < 32; i += 8)
        dst[(size_t)(c0 + ty + i) * DMODEL + r0 + tx] = f2bf(tile[tx][ty + i]);
}

// ---------------------------------------------------------------------------
// Vt transpose: qkv [token][3072] (cols 2048..3071) -> vt [hd][token] bf16
// ---------------------------------------------------------------------------
__global__ __launch_bounds__(256) void vt_transpose_kernel(
    const unsigned short* __restrict__ qkv, unsigned short* __restrict__ vt)
{
    __shared__ unsigned short tile[32][33];
    int c0 = blockIdx.x * 32;   // hd
    int r0 = blockIdx.y * 32;   // token
    int tx = threadIdx.x, ty = threadIdx.y;
    #pragma unroll
    for (int i = 0; i < 32; i += 8)
        tile[ty + i][tx] = qkv[(size_t)(r0 + ty + i) * QKVLD + 2048 + c0 + tx];
    __syncthreads();
    #pragma unroll
    for (int i = 0; i < 32; i += 8)
        vt[(size_t)(c0 + ty + i) * NTOK + r0 + tx] = tile[tx][ty + i];
}

// ---------------------------------------------------------------------------
// f32 -> bf16 flat cast with zero padding
// ---------------------------------------------------------------------------
__global__ __launch_bounds__(256) void cast_pad_kernel(
    const float* __restrict__ in, unsigned short* __restrict__ out,
    long n_src, long n_tot)
{
    long i = ((long)blockIdx.x * 256 + threadIdx.x) * 8;
    if (i >= n_tot) return;
    short8 o8;
    if (i < n_src) {
        const float4* p = (const float4*)(in + i);
        float4 a = p[0], b = p[1];
        o8[0] = (short)f2bf(a.x); o8[1] = (short)f2bf(a.y);
        o8[2] = (short)f2bf(a.z); o8[3] = (short)f2bf(a.w);
        o8[4] = (short)f2bf(b.x); o8[5] = (short)f2bf(b.y);
        o8[6] = (short)f2bf(b.z); o8[7] = (short)f2bf(b.w);
    } else {
        o8 = (short8)0;
    }
    *(short8*)(out + i) = o8;
}

// ---------------------------------------------------------------------------
// mm128: 128x128-tile bf16 MFMA GEMM, BK=32, 4-deep LDS ring (64KB ->
// 2 blocks/CU) + counted vmcnt. Swizzle (row>>1)&3: 0 conflicts (r11/r12 PMC).
// Split-K=2 max (split-K=4 measured +88us total from atomic contention, r16).
// ---------------------------------------------------------------------------
template<bool ATOMIC, bool SILU, bool BF16OUT, int RM>
__global__ __launch_bounds__(256, 2) void mm128_kernel(
    const unsigned short* __restrict__ A, const unsigned short* __restrict__ Bt,
    void* __restrict__ Cv, int M, int N, int K, int rows, int ksplit)
{
    int nwg = gridDim.x;
    int flat = blockIdx.x;
    int q8 = nwg >> 3, r8 = nwg & 7;
    int xcd = flat & 7, lid = flat >> 3;
    int wg = (r8 == 0) ? (xcd * q8 + lid)
           : ((xcd < r8 ? xcd * (q8 + 1) : r8 * (q8 + 1) + (xcd - r8) * q8) + lid);
    int rs = rows * ksplit;
    const int col0 = (wg / rs) * 128;
    int rem = wg % rs;
    const int row0 = (rem / ksplit) * 128;
    const int sk   = rem % ksplit;
    const int Keff = K / ksplit;
    const int kbase = sk * Keff;

    __shared__ __align__(16) char lds[65536];   // 4 bufs x (A 8KB + B 8KB)
    const int tid  = threadIdx.x;
    const int lane = tid & 63;
    const int wave = tid >> 6;
    const int wm = wave >> 1, wn = wave & 1;
    const int g  = lane >> 4;
    const int c  = lane & 15;

    f32x4 acc[4][4] = {};

    auto STAGE = [&](int buf, int t) {
        const int k0 = kbase + t * 32;
        char* base = lds + buf * 16384;
        #pragma unroll
        for (int j = 0; j < 2; ++j) {
            int chunk = j * 256 + tid;
            int row = chunk >> 2, slot = chunk & 3;
            int ss = slot ^ ((row >> 1) & 3);
            __builtin_amdgcn_global_load_lds(
                (const __attribute__((address_space(1))) void*)
                    (A + (size_t)(row0 + row) * K + k0 + ss * 8),
                (__attribute__((address_space(3))) void*)(base + chunk * 16), 16, 0, 0);
        }
        #pragma unroll
        for (int j = 0; j < 2; ++j) {
            int chunk = j * 256 + tid;
            int row = chunk >> 2, slot = chunk & 3;
            int ss = slot ^ ((row >> 1) & 3);
            __builtin_amdgcn_global_load_lds(
                (const __attribute__((address_space(1))) void*)
                    (Bt + (size_t)(col0 + row) * K + k0 + ss * 8),
                (__attribute__((address_space(3))) void*)(base + 8192 + chunk * 16), 16, 0, 0);
        }
    };

    const int NT = Keff >> 5;
    STAGE(0, 0);
    if (NT > 1) STAGE(1, 1);
    if (NT > 2) STAGE(2, 2);
    if (NT > 2)      asm volatile("s_waitcnt vmcnt(8)" ::: "memory");
    else if (NT > 1) asm volatile("s_waitcnt vmcnt(4)" ::: "memory");
    else             asm volatile("s_waitcnt vmcnt(0)" ::: "memory");
    __builtin_amdgcn_s_barrier();
    __builtin_amdgcn_sched_barrier(0);

    for (int t = 0; t < NT; ++t) {
        if (t + 3 < NT) STAGE((t + 3) & 3, t + 3);

        char* base = lds + (t & 3) * 16384;
        short8 af[4], bf[4];
        #pragma unroll
        for (int i = 0; i < 4; ++i) {
            int rowa = wm * 64 + i * 16 + c;
            af[i] = *(const short8*)(base + rowa * 64 + ((g ^ ((rowa >> 1) & 3)) << 4));
            int rowb = wn * 64 + i * 16 + c;
            bf[i] = *(const short8*)(base + 8192 + rowb * 64 + ((g ^ ((rowb >> 1) & 3)) << 4));
        }
        __builtin_amdgcn_s_setprio(1);
        #pragma unroll
        for (int i = 0; i < 4; ++i)
            #pragma unroll
            for (int j = 0; j < 4; ++j)
                acc[i][j] = __builtin_amdgcn_mfma_f32_16x16x32_bf16(
                    af[i], bf[j], acc[i][j], 0, 0, 0);
        __builtin_amdgcn_s_setprio(0);
        __builtin_amdgcn_sched_barrier(0);

        if (t + 1 < NT) {
            if (t + 3 < NT)      asm volatile("s_waitcnt vmcnt(8)" ::: "memory");
            else if (t + 2 < NT) asm volatile("s_waitcnt vmcnt(4)" ::: "memory");
            else                 asm volatile("s_waitcnt vmcnt(0)" ::: "memory");
            __builtin_amdgcn_s_barrier();
            __builtin_amdgcn_sched_barrier(0);
        }
    }

    float* Cf = (float*)Cv;
    unsigned short* Cb = (unsigned short*)Cv;
    const int crow  = row0 + wm * 64 + g * 4;
    const int ccol0 = col0 + wn * 64 + c;
    #pragma unroll
    for (int i = 0; i < 4; ++i) {
        #pragma unroll
        for (int j = 0; j < 4; ++j) {
            int gcol = ccol0 + j * 16;
            if (gcol < N) {
                #pragma unroll
                for (int r = 0; r < 4; ++r) {
                    int grow = crow + i * 16 + r;
                    int orow = RM ? (((grow & (SEQ - 1)) << 1) | (grow >> 10)) : grow;
                    float v = acc[i][j][r];
                    if (SILU) v = v / (1.0f + __expf(-v));
                    size_t ci = (size_t)orow * N + gcol;
                    if (ATOMIC)       atomicAdd(&Cf[ci], v);
                    else if (BF16OUT) Cb[ci] = f2bf(v);
                    else              Cf[ci] = v;
                }
            }
        }
    }
}

// ---------------------------------------------------------------------------
// mm256: 256x256-tile, 8 waves, BK=32, 4-deep LDS ring (128KB, 1 block/CU),
// counted vmcnt, swizzle (row>>1)&3 — proven 306 us / 0 conflicts (r12).
// ---------------------------------------------------------------------------
template<bool SILU, bool BF16OUT, int RM>
__global__ __launch_bounds__(512, 1) void mm256_kernel(
    const unsigned short* __restrict__ A, const unsigned short* __restrict__ Bt,
    void* __restrict__ Cv, int M, int N, int K, int rows)
{
    int nwg = gridDim.x;
    int flat = blockIdx.x;
    int q8 = nwg >> 3, r8 = nwg & 7;
    int xcd = flat & 7, lid = flat >> 3;
    int wg = (r8 == 0) ? (xcd * q8 + lid)
           : ((xcd < r8 ? xcd * (q8 + 1) : r8 * (q8 + 1) + (xcd - r8) * q8) + lid);
    const int row0 = (wg % rows) * 256;
    const int col0 = (wg / rows) * 256;

    __shared__ __align__(16) char lds[131072];   // 4 bufs x (A 16KB + B 16KB)
    const int tid  = threadIdx.x;
    const int lane = tid & 63;
    const int wave = tid >> 6;
    const int wm = wave >> 2;
    const int wn = wave & 3;
    const int g  = lane >> 4;
    const int c  = lane & 15;

    f32x4 acc[8][4] = {};

    auto STAGE = [&](int buf, int tile) {
        const int k0 = tile * 32;
        char* base = lds + buf * 32768;
        #pragma unroll
        for (int j = 0; j < 2; ++j) {
            int chunk = j * 512 + tid;
            int row = chunk >> 2, slot = chunk & 3;
            int sslot = slot ^ ((row >> 1) & 3);
            __builtin_amdgcn_global_load_lds(
                (const __attribute__((address_space(1))) void*)
                    (A + (size_t)(row0 + row) * K + k0 + sslot * 8),
                (__attribute__((address_space(3))) void*)(base + chunk * 16), 16, 0, 0);
        }
        #pragma unroll
        for (int j = 0; j < 2; ++j) {
            int chunk = j * 512 + tid;
            int row = chunk >> 2, slot = chunk & 3;
            int sslot = slot ^ ((row >> 1) & 3);
            __builtin_amdgcn_global_load_lds(
                (const __attribute__((address_space(1))) void*)
                    (Bt + (size_t)(col0 + row) * K + k0 + sslot * 8),
                (__attribute__((address_space(3))) void*)(base + 16384 + chunk * 16), 16, 0, 0);
        }
    };

    const int NT = K >> 5;
    STAGE(0, 0); STAGE(1, 1); STAGE(2, 2);
    asm volatile("s_waitcnt vmcnt(8)" ::: "memory");
    __builtin_amdgcn_s_barrier();
    __builtin_amdgcn_sched_barrier(0);

    for (int t = 0; t < NT; ++t) {
        if (t + 3 < NT) STAGE((t + 3) & 3, t + 3);

        char* base = lds + (t & 3) * 32768;
        short8 af[8], bf[4];
        #pragma unroll
        for (int mf = 0; mf < 8; ++mf) {
            int row = wm * 128 + mf * 16 + c;
            af[mf] = *(const short8*)(base + row * 64 + ((g ^ ((row >> 1) & 3)) << 4));
        }
        #pragma unroll
        for (int nf = 0; nf < 4; ++nf) {
            int row = wn * 64 + nf * 16 + c;
            bf[nf] = *(const short8*)(base + 16384 + row * 64 + ((g ^ ((row >> 1) & 3)) << 4));
        }
        __builtin_amdgcn_s_setprio(1);
        #pragma unroll
        for (int mf = 0; mf < 8; ++mf)
            #pragma unroll
            for (int nf = 0; nf < 4; ++nf)
                acc[mf][nf] = __builtin_amdgcn_mfma_f32_16x16x32_bf16(
                    af[mf], bf[nf], acc[mf][nf], 0, 0, 0);
        __builtin_amdgcn_s_setprio(0);
        __builtin_amdgcn_sched_barrier(0);

        if (t + 1 < NT) {
            if (t + 3 < NT)      asm volatile("s_waitcnt vmcnt(8)" ::: "memory");
            else if (t + 2 < NT) asm volatile("s_waitcnt vmcnt(4)" ::: "memory");
            else                 asm volatile("s_waitcnt vmcnt(0)" ::: "memory");
            __builtin_amdgcn_s_barrier();
            __builtin_amdgcn_sched_barrier(0);
        }
    }

    float* Cf = (float*)Cv;
    unsigned short* Cb = (unsigned short*)Cv;
    #pragma unroll
    for (int mf = 0; mf < 8; ++mf) {
        #pragma unroll
        for (int nf = 0; nf < 4; ++nf) {
            int gcol = col0 + wn * 64 + nf * 16 + c;
            if (gcol < N) {
                #pragma unroll
                for (int r = 0; r < 4; ++r) {
                    int grow = row0 + wm * 128 + mf * 16 + g * 4 + r;
                    int orow = RM ? (((grow & (SEQ - 1)) << 1) | (grow >> 10)) : grow;
                    float v = acc[mf][nf][r];
                    if (SILU) v = v / (1.0f + __expf(-v));
                    size_t ci = (size_t)orow * N + gcol;
                    if (BF16OUT) Cb[ci] = f2bf(v);
                    else         Cf[ci] = v;
                }
            }
        }
    }
}

// ---------------------------------------------------------------------------
// Flash attention (bf16 MFMA). q,k from fused qkv (stride QKVLD); vt [hd][tok].
// ---------------------------------------------------------------------------
__global__ __launch_bounds__(256) void flash_attn_kernel(
    const unsigned short* __restrict__ q, const unsigned short* __restrict__ k,
    const unsigned short* __restrict__ vt, unsigned short* __restrict__ o)
{
    const int qt   = blockIdx.x;
    const int h    = blockIdx.y;
    const int b    = blockIdx.z;
    const int tid  = threadIdx.x;
    const int lane = tid & 63;
    const int wave = tid >> 6;
    const int g    = lane >> 4;
    const int c    = lane & 15;

    __shared__ unsigned short k_lds[64 * 128];
    __shared__ unsigned short vt_lds[128 * 64];
    __shared__ unsigned short p_lds[4 * 16 * 64];

    const int q0  = qt * 64;
    const int wq0 = q0 + wave * 16;
    const int tokb = b * SEQ;

    short8 qf[4];
    {
        const unsigned short* qr =
            q + (size_t)(tokb + wq0 + c) * QKVLD + h * HDIM + g * 8;
        #pragma unroll
        for (int dblk = 0; dblk < 4; ++dblk)
            qf[dblk] = *(const short8*)(qr + dblk * 32);
    }

    f32x4 oacc[8] = {};
    float m = -1e30f, l = 0.f;
    const float scale = 0.08838834764831845f;
    const int myq = wq0 + c;

    const int nt = qt + 1;
    for (int it = 0; it < nt; ++it) {
        const int kv0 = it * 64;
        short8 kc[4], vc[4];
        #pragma unroll
        for (int i = 0; i < 4; ++i) {
            int chunk = tid + i * 256;
            int key = chunk >> 4, cc = chunk & 15;
            kc[i] = *(const short8*)(
                k + (size_t)(tokb + kv0 + key) * QKVLD + h * HDIM + cc * 8);
        }
        #pragma unroll
        for (int i = 0; i < 4; ++i) {
            int chunk = tid + i * 256;
            int d = chunk >> 3, cc = chunk & 7;
            vc[i] = *(const short8*)(
                vt + (size_t)(h * HDIM + d) * NTOK + tokb + kv0 + cc * 8);
        }
        __syncthreads();
        #pragma unroll
        for (int i = 0; i < 4; ++i) {
            int chunk = tid + i * 256;
            int key = chunk >> 4, cc = chunk & 15;
            *(short8*)((char*)k_lds + ((key * 256 + cc * 16) ^ ((key & 7) << 4))) = kc[i];
        }
        #pragma unroll
        for (int i = 0; i < 4; ++i) {
            int chunk = tid + i * 256;
            int d = chunk >> 3, cc = chunk & 7;
            *(short8*)((char*)vt_lds + ((d * 128 + cc * 16) ^ ((d & 7) << 4))) = vc[i];
        }
        __syncthreads();

        f32x4 st[4];
        #pragma unroll
        for (int sub = 0; sub < 4; ++sub) {
            f32x4 acc = {};
            int key = sub * 16 + c;
            #pragma unroll
            for (int dblk = 0; dblk < 4; ++dblk) {
                short8 kf = *(const short8*)((char*)k_lds +
                    ((key * 256 + dblk * 64 + g * 16) ^ ((key & 7) << 4)));
                acc = __builtin_amdgcn_mfma_f32_16x16x32_bf16(kf, qf[dblk], acc, 0, 0, 0);
            }
            st[sub] = acc;
        }

        #pragma unroll
        for (int sub = 0; sub < 4; ++sub)
            #pragma unroll
            for (int r = 0; r < 4; ++r) {
                int key = kv0 + sub * 16 + g * 4 + r;
                float s = st[sub][r] * scale;
                st[sub][r] = (key <= myq) ? s : -1e30f;
            }

        float tm = -1e30f;
        #pragma unroll
        for (int sub = 0; sub < 4; ++sub)
            #pragma unroll
            for (int r = 0; r < 4; ++r) tm = fmaxf(tm, st[sub][r]);
        tm = fmaxf(tm, __shfl_xor(tm, 16));
        tm = fmaxf(tm, __shfl_xor(tm, 32));
        float mnew = fmaxf(m, tm);
        float sc_f = __expf(m - mnew);
        m = mnew;

        float ps = 0.f;
        #pragma unroll
        for (int sub = 0; sub < 4; ++sub) {
            float p0 = __expf(st[sub][0] - m);
            float p1 = __expf(st[sub][1] - m);
            float p2 = __expf(st[sub][2] - m);
            float p3 = __expf(st[sub][3] - m);
            ps += (p0 + p1) + (p2 + p3);
            ushort4 pk;
            pk.x = f2bf(p0); pk.y = f2bf(p1); pk.z = f2bf(p2); pk.w = f2bf(p3);
            *(ushort4*)((char*)p_lds + wave * 2048 +
                ((c * 128 + sub * 32 + g * 8) ^ ((c & 7) << 4))) = pk;
        }
        ps += __shfl_xor(ps, 16);
        ps += __shfl_xor(ps, 32);
        l = l * sc_f + ps;
        #pragma unroll
        for (int dt = 0; dt < 8; ++dt)
            #pragma unroll
            for (int r = 0; r < 4; ++r) oacc[dt][r] *= sc_f;

        #pragma unroll
        for (int kb = 0; kb < 2; ++kb) {
            short8 pf = *(const short8*)((char*)p_lds + wave * 2048 +
                ((c * 128 + kb * 64 + g * 16) ^ ((c & 7) << 4)));
            #pragma unroll
            for (int dt = 0; dt < 8; ++dt) {
                int d = dt * 16 + c;
                short8 vf = *(const short8*)((char*)vt_lds +
                    ((d * 128 + kb * 64 + g * 16) ^ ((d & 7) << 4)));
                oacc[dt] = __builtin_amdgcn_mfma_f32_16x16x32_bf16(vf, pf, oacc[dt], 0, 0, 0);
            }
        }
    }

    float inv = 1.0f / l;
    unsigned short* orow = o + (size_t)(tokb + wq0 + c) * DMODEL + h * HDIM + g * 4;
    #pragma unroll
    for (int dt = 0; dt < 8; ++dt) {
        ushort4 ov;
        ov.x = f2bf(oacc[dt][0] * inv);
        ov.y = f2bf(oacc[dt][1] * inv);
        ov.z = f2bf(oacc[dt][2] * inv);
        ov.w = f2bf(oacc[dt][3] * inv);
        *(ushort4*)(orow + dt * 16) = ov;
    }
}

// ---------------------------------------------------------------------------
// Launch
// ---------------------------------------------------------------------------
extern "C" void kernel_launch(void* const* d_in, const int* in_sizes, int n_in,
                              void* d_out, int out_size, void* d_ws, size_t ws_size,
                              hipStream_t stream)
{
    const int*   tokens       = (const int*)  d_in[0];
    const float* tok_emb      = (const float*)d_in[1];
    const float* pos_emb      = (const float*)d_in[2];
    const float* attn_norm_w  = (const float*)d_in[3];
    const float* Wq           = (const float*)d_in[4];
    const float* Wk           = (const float*)d_in[5];
    const float* Wv           = (const float*)d_in[6];
    const float* Wo           = (const float*)d_in[7];
    const float* mlp_norm_w   = (const float*)d_in[8];
    const float* W1           = (const float*)d_in[9];
    const float* W2           = (const float*)d_in[10];
    const float* final_norm_w = (const float*)d_in[11];
    float* out = (float*)d_out;

    // ---- workspace layout ----
    char* wp = (char*)d_ws;
    size_t off = 0;
    auto alloc = [&](size_t bytes) -> void* {
        void* p = wp + off;
        off += (bytes + 255) & ~(size_t)255;
        return p;
    };
    float* x             = (float*)alloc((size_t)NTOK * DMODEL * 4);
    unsigned short* nbf     = (unsigned short*)alloc((size_t)NTOK * DMODEL * 2);
    unsigned short* qkvbf   = (unsigned short*)alloc((size_t)NTOK * QKVLD * 2);
    unsigned short* vtb     = (unsigned short*)alloc((size_t)DMODEL * NTOK * 2);
    unsigned short* attnbf  = (unsigned short*)alloc((size_t)NTOK * DMODEL * 2);
    unsigned short* hbf     = (unsigned short*)alloc((size_t)NTOK * FFDIM * 2);
    unsigned short* temb    = (unsigned short*)alloc((size_t)VPAD * DMODEL * 2);
    unsigned short* Wqkv_t  = (unsigned short*)alloc((size_t)NLAYER * QKVLD * DMODEL * 2);
    unsigned short* Wo_t    = (unsigned short*)alloc((size_t)NLAYER * DMODEL * DMODEL * 2);
    unsigned short* W1_t    = (unsigned short*)alloc((size_t)NLAYER * DMODEL * FFDIM * 2);
    unsigned short* W2_t    = (unsigned short*)alloc((size_t)NLAYER * FFDIM * DMODEL * 2);
    if (off > ws_size) return;

    // ---- weight prep ----
    {
        dim3 bb(32, 8), g(HDIM / 32, DMODEL / 32, NLAYER * NHEAD);
        transpose_qkv_kernel<<<g, bb, 0, stream>>>(Wq, Wqkv_t, 0);
        transpose_qkv_kernel<<<g, bb, 0, stream>>>(Wk, Wqkv_t, DMODEL);
        transpose_qkv_kernel<<<g, bb, 0, stream>>>(Wv, Wqkv_t, 2 * DMODEL);
    }
    {
        dim3 bb(32, 8), g(DMODEL / 32, DMODEL / 32, NLAYER);
        transpose_cast_kernel<<<g, bb, 0, stream>>>(Wo, Wo_t, DMODEL, DMODEL);
    }
    {
        dim3 bb(32, 8), g(FFDIM / 32, DMODEL / 32, NLAYER);
        transpose_cast_kernel<<<g, bb, 0, stream>>>(W1, W1_t, DMODEL, FFDIM);
    }
    {
        dim3 bb(32, 8), g(DMODEL / 32, FFDIM / 32, NLAYER);
        transpose_cast_kernel<<<g, bb, 0, stream>>>(W2, W2_t, FFDIM, DMODEL);
    }
    {
        long n_src = (long)VOCAB * DMODEL, n_tot = (long)VPAD * DMODEL;
        cast_pad_kernel<<<(unsigned)(n_tot / 8 / 256), 256, 0, stream>>>(
            tok_emb, temb, n_src, n_tot);
    }

    // ---- embed ----
    embed_kernel<<<(NTOK * DMODEL) / 256, 256, 0, stream>>>(tokens, tok_emb, pos_emb, x);

    const size_t LW    = (size_t)DMODEL * DMODEL;
    const size_t LWQKV = (size_t)QKVLD * DMODEL;
    const size_t LWF   = (size_t)DMODEL * FFDIM;

    for (int l = 0; l < NLAYER; l++) {
        rmsnorm_bf_kernel<<<NTOK / 4, 256, 0, stream>>>(
            x, attn_norm_w + (size_t)l * DMODEL, nbf);
        // fused qkv: [NTOK][3072], 24 cols x 16 rows = 384 blocks
        mm128_kernel<false, false, true, 0><<<384, 256, 0, stream>>>(
            nbf, Wqkv_t + l * LWQKV, qkvbf, NTOK, QKVLD, DMODEL, 16, 1);
        vt_transpose_kernel<<<dim3(DMODEL / 32, NTOK / 32), dim3(32, 8), 0, stream>>>(
            qkvbf, vtb);
        flash_attn_kernel<<<dim3(SEQ / 64, NHEAD, BATCH), 256, 0, stream>>>(
            qkvbf, qkvbf + DMODEL, vtb, attnbf);
        // out proj: split-K=2, atomic f32 accumulate into residual x
        mm128_kernel<true, false, false, 0><<<8 * 16 * 2, 256, 0, stream>>>(
            attnbf, Wo_t + l * LW, x, NTOK, DMODEL, DMODEL, 16, 2);
        rmsnorm_bf_kernel<<<NTOK / 4, 256, 0, stream>>>(
            x, mlp_norm_w + (size_t)l * DMODEL, nbf);
        // h = silu(n @ W1): 32 cols x 16 rows = 512 blocks
        mm128_kernel<false, true, true, 0><<<32 * 16, 256, 0, stream>>>(
            nbf, W1_t + l * LWF, hbf, NTOK, FFDIM, DMODEL, 16, 1);
        // x += h @ W2: split-K=2
        mm128_kernel<true, false, false, 0><<<8 * 16 * 2, 256, 0, stream>>>(
            hbf, W2_t + l * LWF, x, NTOK, DMODEL, FFDIM, 16, 2);
    }

    rmsnorm_bf_kernel<<<NTOK / 4, 256, 0, stream>>>(x, final_norm_w, nbf);
    // lm-head: mm256 4-ring (proven 306 us), 8 rows x 197 cols = 1576 blocks
    mm256_kernel<false, false, 1><<<8 * 197, 512, 0, stream>>>(
        nbf, temb, out, NTOK, VOCAB, DMODEL, 8);
}